// Round 1
// 112.580 us; speedup vs baseline: 1.0101x; 1.0101x over previous
//
#include <hip/hip_runtime.h>
#include <math.h>

#define NB 8
#define NQ 256
#define NK 256
#define DIN 10
#define FDIM 64
#define HIDDEN 256
#define NH 8
#define ROWS_PER_BLK 4

#define FSTRIDE 64    // shorts per feat row; XOR-swizzled 8-short col-blocks, no pad
#define HSTRIDE 264   // shorts per h row (256 + 8 pad) -> 528 B
#define W2S 264       // shorts per w2 row (8 rows, padded -> 528 B)

typedef float f32x4 __attribute__((ext_vector_type(4)));
typedef short bf16x8 __attribute__((ext_vector_type(8)));

// fast float->bf16: round-to-nearest, ties away (2 instrs)
__device__ __forceinline__ short f2bf(float f) {
    return (short)((__float_as_uint(f) + 0x8000u) >> 16);
}
// pack two floats -> two bf16 in one dword (2 adds + 1 perm)
__device__ __forceinline__ unsigned pack2(float a, float b) {
    unsigned ua = __float_as_uint(a) + 0x8000u;   // -> low half
    unsigned ub = __float_as_uint(b) + 0x8000u;   // -> high half
    return __builtin_amdgcn_perm(ub, ua, 0x07060302);
}

__device__ __forceinline__ void four4(float x, float* dst) {
    float s1 = __sinf(x), c1 = __cosf(x);
    float s2 = 2.f * s1 * c1, c2 = 1.f - 2.f * s1 * s1;
    float s4 = 2.f * s2 * c2, c4 = 1.f - 2.f * s2 * s2;
    float s8 = 2.f * s4 * c4, c8 = 1.f - 2.f * s4 * s4;
    dst[0] = s1; dst[1] = s2; dst[2] = s4; dst[3] = s8;
    dst[4] = c1; dst[5] = c2; dst[6] = c4; dst[7] = c8;
}
__device__ __forceinline__ void four2(float x, float* dst) {
    float s1 = __sinf(x), c1 = __cosf(x);
    dst[0] = s1; dst[1] = 2.f * s1 * c1;
    dst[2] = c1; dst[3] = 1.f - 2.f * s1 * s1;
}

// Block = one (b, i0..i0+3): FOUR query rows, 256 pairs each; EIGHT waves.
// Grid = 512 = 2 blocks/CU resident -> 16 waves/CU (was 8). LDS unchanged.
// Re-sharding vs r-prev (proven 4-wave pipeline):
//   - GEMM1: wave owns 32 hidden (nt<2), acc[2][4], w1f[2][2]  (VGPR halves)
//   - features: 2 threads/pair; half0 = c8 {0,1,6,7}, half1 = c8 {2,3,4,5}
//     (balanced sincos; four2(dist) reuses four4(dist) s/c; same_team via
//      cndmask constants - no trig)
//   - silu: 32 values/thread/chunk (halved serial trans chain)
//   - GEMM2: waves 0-3 only (wave-uniform skip for 4-7; idle covered by
//     occupancy, no extra barrier or reduce buffer)
// Scale folds unchanged: W1,b1 pre-scaled by -log2(e); W2 by -ln(2).
__global__ __launch_bounds__(512, 4) void relfeat_mfma_kernel(
    const float* __restrict__ q, const float* __restrict__ k,
    const float* __restrict__ W1, const float* __restrict__ b1,
    const float* __restrict__ W2, const float* __restrict__ b2,
    float* __restrict__ out)
{
    __shared__ __align__(16) short feat_s[NK * FSTRIDE];   // 32768 B
    __shared__ __align__(16) short h_s[64 * HSTRIDE];      // 33792 B
    __shared__ __align__(16) short w2_s[8 * W2S];          //  4224 B

    const int t = threadIdx.x;          // 0..511
    const int wave = t >> 6;            // 0..7
    const int lane15 = t & 15;
    const int quad = (t >> 4) & 3;
    const int p = t & 255;              // pair id for features / staging
    const int half = t >> 8;            // 0/1: which half of features
    const int b = blockIdx.x >> 6;
    const int i0 = (blockIdx.x & 63) * ROWS_PER_BLK;

    // ---- k-row for pair j = p: block-invariant, cache in regs ----
    const float* kp = k + ((size_t)b * NK + p) * DIN;
    const float k0 = kp[0], k3 = kp[3], k4 = kp[4], k5 = kp[5], k6 = kp[6],
                k7 = kp[7], k8 = kp[8];

    // ---- stage W2^T scaled by -ln2 (o-major, padded stride) ----
#pragma unroll
    for (int o2 = 0; o2 < 4; ++o2) {
        const int o = half * 4 + o2;
        w2_s[o * W2S + p] = f2bf(-0.69314718f * W2[p * NH + o]);
    }

    // ---- W1 fragments (A operand), scaled by -log2e; one-time, L2-hot ----
    const int n0 = wave * 32;
    bf16x8 w1f[2][2];
#pragma unroll
    for (int nt = 0; nt < 2; ++nt)
#pragma unroll
        for (int ks = 0; ks < 2; ++ks) {
            const float* wp = W1 + (size_t)(ks * 32 + quad * 8) * HIDDEN
                              + (n0 + nt * 16 + lane15);
            bf16x8 v;
#pragma unroll
            for (int e = 0; e < 8; ++e)
                v[e] = f2bf(-1.44269504f * wp[(size_t)e * HIDDEN]);
            w1f[nt][ks] = v;
        }
    // bias per (nt, r), scaled by -log2e
    float4 b1q[2];
#pragma unroll
    for (int nt = 0; nt < 2; ++nt) {
        float4 bb = *(const float4*)&b1[n0 + nt * 16 + quad * 4];
        b1q[nt] = make_float4(-1.44269504f * bb.x, -1.44269504f * bb.y,
                              -1.44269504f * bb.z, -1.44269504f * bb.w);
    }
    const float b2v = (lane15 < NH) ? b2[lane15] : 0.f;

    const int sw = p & 7;        // feature-store swizzle
    const int swr = lane15 & 7;  // feat B-frag read swizzle

    // ================= row loop: 4 query rows =================
#pragma unroll 1
    for (int row = 0; row < ROWS_PER_BLK; ++row) {
        const int i = i0 + row;

        // ---- features for pair (i, j=p): proven math, 2 threads/pair ----
        {
            const float* qp = q + ((size_t)b * NQ + i) * DIN;
            const float q0 = qp[0], q3 = qp[3], q4 = qp[4], q5 = qp[5],
                        q6 = qp[6], q7 = qp[7], q8 = qp[8];

            const float dpx = k3 - q3, dpy = k4 - q4;
            const float dvx = k5 - q5, dvy = k6 - q6;
            const float dist = sqrtf(dpx * dpx + dpy * dpy + 1e-6f);

            float feat[32];
            if (half == 0) {
                // c8 {0,1,6,7}: dist4 | inv_dist4 | ttca2+dist2 | team2+dspeed2
                const float inv_dist = 1.0f / (dist + 0.1f);
                const float dot_dp_dv = dpx * dvx + dpy * dvy;
                const float speed_sq = dvx * dvx + dvy * dvy;
                const float ttca = tanhf(fmaxf(0.f, -dot_dp_dv / (speed_sq + 1e-6f)));
                const float q_speed = sqrtf(q5 * q5 + q6 * q6);
                const float k_speed = sqrtf(k5 * k5 + k6 * k6);
                const float delta_speed = k_speed - q_speed;
                four4(dist,     feat + 0);
                four4(inv_dist, feat + 8);
                four2(ttca,     feat + 16);
                // four2(dist) = subset of four4(dist): reuse, no trig
                feat[20] = feat[0]; feat[21] = feat[1];
                feat[22] = feat[4]; feat[23] = feat[5];
                // same_team in {0,1}: fourier values are constants, select
                const bool st = (q0 == k0);
                feat[24] = st ? 0.84147098f : 0.f;    // sin(1), sin(0)
                feat[25] = st ? 0.90929743f : 0.f;    // sin(2), sin(0)
                feat[26] = st ? 0.54030231f : 1.f;    // cos(1), cos(0)
                feat[27] = st ? -0.41614684f : 1.f;   // cos(2), cos(0)
                four2(delta_speed, feat + 28);
            } else {
                // c8 {2,3,4,5}: ata4 | aspect4 | dpx2+dpy2 | dvx2+dvy2
                const float inv_d2 = 1.0f / (dist + 1e-6f);
                const float bear_x = dpx * inv_d2, bear_y = dpy * inv_d2;
                const float ata = bear_x * q7 + bear_y * q8;
                const float aspect = bear_x * k7 + bear_y * k8;
                four4(ata,    feat + 0);
                four4(aspect, feat + 8);
                four2(dpx,    feat + 16);
                four2(dpy,    feat + 20);
                four2(dvx,    feat + 24);
                four2(dvy,    feat + 28);
            }
#pragma unroll
            for (int j = 0; j < 4; ++j) {
                // half0 -> c8 {0,1,6,7}; half1 -> c8 {2,3,4,5} (arith, no LUT)
                const int c8 = half ? (j + 2) : (j < 2 ? j : j + 4);
                uint4 v;
                v.x = pack2(feat[j * 8 + 0], feat[j * 8 + 1]);
                v.y = pack2(feat[j * 8 + 2], feat[j * 8 + 3]);
                v.z = pack2(feat[j * 8 + 4], feat[j * 8 + 5]);
                v.w = pack2(feat[j * 8 + 6], feat[j * 8 + 7]);
                *(uint4*)&feat_s[p * FSTRIDE + ((c8 ^ sw) * 8)] = v;
            }
        }
        // Safe: all feat_s readers of row-1 finished before row-1's last
        // pre-silu barrier; all h_s readers finished before this barrier.
        __syncthreads();  // feat_s(row) + (row 0: w2_s) ready

        // ---- 4 chunks of 64 pairs ----
#pragma unroll 1
        for (int c = 0; c < 4; ++c) {
            const int p0 = c * 64;

            // GEMM1': acc[nt][mt] -> D[hidden=n0+nt*16+quad*4+r][pair=p0+mt*16+lane15]
            f32x4 acc[2][4];
#pragma unroll
            for (int nt = 0; nt < 2; ++nt)
#pragma unroll
                for (int mt = 0; mt < 4; ++mt)
                    acc[nt][mt] = (f32x4){b1q[nt].x, b1q[nt].y, b1q[nt].z, b1q[nt].w};
#pragma unroll
            for (int ks = 0; ks < 2; ++ks)
#pragma unroll
                for (int mt = 0; mt < 4; ++mt) {
                    const int r2 = p0 + mt * 16 + lane15;
                    const bf16x8 fb = *(const bf16x8*)
                        &feat_s[r2 * FSTRIDE + (((ks * 4 + quad) ^ swr) * 8)];
#pragma unroll
                    for (int nt = 0; nt < 2; ++nt)
                        acc[nt][mt] = __builtin_amdgcn_mfma_f32_16x16x32_bf16(
                            w1f[nt][ks], fb, acc[nt][mt], 0, 0, 0);
                }

            __syncthreads();  // h_s(prev) fully consumed before overwrite

            // silu (scale-folded, 4 instrs) -> pack -> one ds_write_b64
#pragma unroll
            for (int nt = 0; nt < 2; ++nt)
#pragma unroll
                for (int mt = 0; mt < 4; ++mt) {
                    const int pair = mt * 16 + lane15;
                    const int hbase = n0 + nt * 16 + quad * 4;
                    float s[4];
#pragma unroll
                    for (int r = 0; r < 4; ++r) {
                        const float a = acc[nt][mt][r];     // = -log2e * preact
                        const float e = __builtin_amdgcn_exp2f(a);
                        s[r] = a * __builtin_amdgcn_rcpf(1.f + e);  // -1.4427*silu
                    }
                    uint2 pk;
                    pk.x = pack2(s[0], s[1]);
                    pk.y = pack2(s[2], s[3]);
                    *(uint2*)&h_s[pair * HSTRIDE + hbase] = pk;
                }
            __syncthreads();  // h_s(c) ready

            // GEMM2: waves 0-3, one 16-pair M-tile each; K=256; W2 carries -ln2
            if (wave < 4) {
                const int pw = wave * 16;
                f32x4 acc2 = (f32x4){b2v, b2v, b2v, b2v};
#pragma unroll
                for (int ks = 0; ks < 8; ++ks) {
                    const bf16x8 ha = *(const bf16x8*)&h_s[(pw + lane15) * HSTRIDE
                                                            + ks * 32 + quad * 8];
                    const bf16x8 wb = *(const bf16x8*)&w2_s[(lane15 & 7) * W2S
                                                             + ks * 32 + quad * 8];
                    acc2 = __builtin_amdgcn_mfma_f32_16x16x32_bf16(ha, wb, acc2, 0, 0, 0);
                }
                if (lane15 < NH) {
                    float* op = out + (((size_t)b * NH + lane15) * NQ + i) * NK
                                + (p0 + pw + quad * 4);
                    *(float4*)op = make_float4(acc2[0], acc2[1], acc2[2], acc2[3]);
                }
            }
            // no end barrier: next chunk's GEMM1' touches only feat_s
        }
    }
}

extern "C" void kernel_launch(void* const* d_in, const int* in_sizes, int n_in,
                              void* d_out, int out_size, void* d_ws, size_t ws_size,
                              hipStream_t stream) {
    const float* q  = (const float*)d_in[0];
    const float* k  = (const float*)d_in[1];
    const float* W1 = (const float*)d_in[2];
    const float* b1 = (const float*)d_in[3];
    const float* W2 = (const float*)d_in[4];
    const float* b2 = (const float*)d_in[5];
    float* out = (float*)d_out;

    dim3 grid(NB * NQ / ROWS_PER_BLK);  // 512 blocks = 2/CU, one dispatch round
    dim3 block(512);                    // 8 waves: 16 waves/CU resident
    relfeat_mfma_kernel<<<grid, block, 0, stream>>>(q, k, W1, b1, W2, b2, out);
}

// Round 2
// 110.366 us; speedup vs baseline: 1.0304x; 1.0201x over previous
//
#include <hip/hip_runtime.h>
#include <math.h>

#define NB 8
#define NQ 256
#define NK 256
#define DIN 10
#define FDIM 64
#define HIDDEN 256
#define NH 8
#define ROWS_PER_BLK 4

#define FSTRIDE 64    // shorts per feat row; XOR-swizzled 8-short col-blocks, no pad
#define HSTRIDE 264   // shorts per h row (256 + 8 pad) -> 528 B

typedef float f32x4 __attribute__((ext_vector_type(4)));
typedef short bf16x8 __attribute__((ext_vector_type(8)));

// fast float->bf16: round-to-nearest, ties away (2 instrs) - staging only
__device__ __forceinline__ short f2bf(float f) {
    return (short)((__float_as_uint(f) + 0x8000u) >> 16);
}
// pack two floats -> two bf16 in ONE instr (RTNE). a -> low half, b -> high.
__device__ __forceinline__ unsigned cvtpk(float a, float b) {
    unsigned r;
    asm("v_cvt_pk_bf16_f32 %0, %1, %2" : "=v"(r) : "v"(a), "v"(b));
    return r;
}

__device__ __forceinline__ void four4(float x, float* dst) {
    float s1 = __sinf(x), c1 = __cosf(x);
    float s2 = 2.f * s1 * c1, c2 = 1.f - 2.f * s1 * s1;
    float s4 = 2.f * s2 * c2, c4 = 1.f - 2.f * s2 * s2;
    float s8 = 2.f * s4 * c4, c8 = 1.f - 2.f * s4 * s4;
    dst[0] = s1; dst[1] = s2; dst[2] = s4; dst[3] = s8;
    dst[4] = c1; dst[5] = c2; dst[6] = c4; dst[7] = c8;
}
__device__ __forceinline__ void four2(float x, float* dst) {
    float s1 = __sinf(x), c1 = __cosf(x);
    dst[0] = s1; dst[1] = 2.f * s1 * c1;
    dst[2] = c1; dst[3] = 1.f - 2.f * s1 * s1;
}

// Block = one (b, i0..i0+3): FOUR query rows, 256 pairs each; EIGHT waves.
// Grid = 512 = 2 blocks/CU resident -> 16 waves/CU. LDS 66560 B.
// r2 changes vs r1 (r1 showed issue-count-bound, not occupancy-bound):
//   - silu SPLIT: trans+pack computed into regs BEFORE barrier#1 (reads only
//     acc regs); only 8 ds_write_b64 remain between the two barriers ->
//     trans burst overlaps GEMM2(c-1) instead of running in lockstep.
//   - v_cvt_pk_bf16_f32 (1 instr) replaces pack2 (3 instr) in silu + feat
//     packing: -12.5% issued instrs.
//   - W2 fragments hoisted to regs from global (once/block, waves 0-3);
//     w2_s LDS deleted; -8 ds_read_b128/chunk in GEMM2.
// Scale folds unchanged: W1,b1 pre-scaled by -log2(e); W2 by -ln(2).
__global__ __launch_bounds__(512, 4) void relfeat_mfma_kernel(
    const float* __restrict__ q, const float* __restrict__ k,
    const float* __restrict__ W1, const float* __restrict__ b1,
    const float* __restrict__ W2, const float* __restrict__ b2,
    float* __restrict__ out)
{
    __shared__ __align__(16) short feat_s[NK * FSTRIDE];   // 32768 B
    __shared__ __align__(16) short h_s[64 * HSTRIDE];      // 33792 B

    const int t = threadIdx.x;          // 0..511
    const int wave = t >> 6;            // 0..7
    const int lane15 = t & 15;
    const int quad = (t >> 4) & 3;
    const int p = t & 255;              // pair id for features / staging
    const int half = t >> 8;            // 0/1: which half of features
    const int b = blockIdx.x >> 6;
    const int i0 = (blockIdx.x & 63) * ROWS_PER_BLK;

    // ---- k-row for pair j = p: block-invariant, cache in regs ----
    const float* kp = k + ((size_t)b * NK + p) * DIN;
    const float k0 = kp[0], k3 = kp[3], k4 = kp[4], k5 = kp[5], k6 = kp[6],
                k7 = kp[7], k8 = kp[8];
    const float k_speed = sqrtf(k5 * k5 + k6 * k6);   // row-invariant, hoisted

    // ---- W2 fragments in regs (GEMM2 B-operand), scaled by -ln2 ----
    // wb[ks][e] = -ln2 * W2[(ks*32 + quad*8 + e)][lane15 & 7]; once, L2-hot.
    bf16x8 w2f[8];
    if (wave < 4) {
#pragma unroll
        for (int ks = 0; ks < 8; ++ks) {
            const float* wp = W2 + (size_t)(ks * 32 + quad * 8) * NH + (lane15 & 7);
            bf16x8 v;
#pragma unroll
            for (int e = 0; e < 8; ++e)
                v[e] = f2bf(-0.69314718f * wp[(size_t)e * NH]);
            w2f[ks] = v;
        }
    }

    // ---- W1 fragments (A operand), scaled by -log2e; one-time, L2-hot ----
    const int n0 = wave * 32;
    bf16x8 w1f[2][2];
#pragma unroll
    for (int nt = 0; nt < 2; ++nt)
#pragma unroll
        for (int ks = 0; ks < 2; ++ks) {
            const float* wp = W1 + (size_t)(ks * 32 + quad * 8) * HIDDEN
                              + (n0 + nt * 16 + lane15);
            bf16x8 v;
#pragma unroll
            for (int e = 0; e < 8; ++e)
                v[e] = f2bf(-1.44269504f * wp[(size_t)e * HIDDEN]);
            w1f[nt][ks] = v;
        }
    // bias per (nt, r), scaled by -log2e
    float4 b1q[2];
#pragma unroll
    for (int nt = 0; nt < 2; ++nt) {
        float4 bb = *(const float4*)&b1[n0 + nt * 16 + quad * 4];
        b1q[nt] = make_float4(-1.44269504f * bb.x, -1.44269504f * bb.y,
                              -1.44269504f * bb.z, -1.44269504f * bb.w);
    }
    const float b2v = (lane15 < NH) ? b2[lane15] : 0.f;

    const int sw = p & 7;        // feature-store swizzle
    const int swr = lane15 & 7;  // feat B-frag read swizzle

    // ================= row loop: 4 query rows =================
#pragma unroll 1
    for (int row = 0; row < ROWS_PER_BLK; ++row) {
        const int i = i0 + row;

        // ---- features for pair (i, j=p): proven math, 2 threads/pair ----
        {
            const float* qp = q + ((size_t)b * NQ + i) * DIN;
            const float q0 = qp[0], q3 = qp[3], q4 = qp[4], q5 = qp[5],
                        q6 = qp[6], q7 = qp[7], q8 = qp[8];

            const float dpx = k3 - q3, dpy = k4 - q4;
            const float dvx = k5 - q5, dvy = k6 - q6;
            const float dist = sqrtf(dpx * dpx + dpy * dpy + 1e-6f);

            float feat[32];
            if (half == 0) {
                // c8 {0,1,6,7}: dist4 | inv_dist4 | ttca2+dist2 | team2+dspeed2
                const float inv_dist = 1.0f / (dist + 0.1f);
                const float dot_dp_dv = dpx * dvx + dpy * dvy;
                const float speed_sq = dvx * dvx + dvy * dvy;
                const float ttca = tanhf(fmaxf(0.f, -dot_dp_dv / (speed_sq + 1e-6f)));
                const float q_speed = sqrtf(q5 * q5 + q6 * q6);
                const float delta_speed = k_speed - q_speed;
                four4(dist,     feat + 0);
                four4(inv_dist, feat + 8);
                four2(ttca,     feat + 16);
                // four2(dist) = subset of four4(dist): reuse, no trig
                feat[20] = feat[0]; feat[21] = feat[1];
                feat[22] = feat[4]; feat[23] = feat[5];
                // same_team in {0,1}: fourier values are constants, select
                const bool st = (q0 == k0);
                feat[24] = st ? 0.84147098f : 0.f;    // sin(1), sin(0)
                feat[25] = st ? 0.90929743f : 0.f;    // sin(2), sin(0)
                feat[26] = st ? 0.54030231f : 1.f;    // cos(1), cos(0)
                feat[27] = st ? -0.41614684f : 1.f;   // cos(2), cos(0)
                four2(delta_speed, feat + 28);
            } else {
                // c8 {2,3,4,5}: ata4 | aspect4 | dpx2+dpy2 | dvx2+dvy2
                const float inv_d2 = 1.0f / (dist + 1e-6f);
                const float bear_x = dpx * inv_d2, bear_y = dpy * inv_d2;
                const float ata = bear_x * q7 + bear_y * q8;
                const float aspect = bear_x * k7 + bear_y * k8;
                four4(ata,    feat + 0);
                four4(aspect, feat + 8);
                four2(dpx,    feat + 16);
                four2(dpy,    feat + 20);
                four2(dvx,    feat + 24);
                four2(dvy,    feat + 28);
            }
#pragma unroll
            for (int j = 0; j < 4; ++j) {
                // half0 -> c8 {0,1,6,7}; half1 -> c8 {2,3,4,5} (arith, no LUT)
                const int c8 = half ? (j + 2) : (j < 2 ? j : j + 4);
                uint4 v;
                v.x = cvtpk(feat[j * 8 + 0], feat[j * 8 + 1]);
                v.y = cvtpk(feat[j * 8 + 2], feat[j * 8 + 3]);
                v.z = cvtpk(feat[j * 8 + 4], feat[j * 8 + 5]);
                v.w = cvtpk(feat[j * 8 + 6], feat[j * 8 + 7]);
                *(uint4*)&feat_s[p * FSTRIDE + ((c8 ^ sw) * 8)] = v;
            }
        }
        // Safe: all feat_s readers of row-1 finished before row-1's last
        // pre-write barrier; all h_s readers finished before this barrier.
        __syncthreads();  // feat_s(row) ready

        // ---- 4 chunks of 64 pairs ----
#pragma unroll 1
        for (int c = 0; c < 4; ++c) {
            const int p0 = c * 64;

            // GEMM1': acc[nt][mt] -> D[hidden=n0+nt*16+quad*4+r][pair=p0+mt*16+lane15]
            f32x4 acc[2][4];
#pragma unroll
            for (int nt = 0; nt < 2; ++nt)
#pragma unroll
                for (int mt = 0; mt < 4; ++mt)
                    acc[nt][mt] = (f32x4){b1q[nt].x, b1q[nt].y, b1q[nt].z, b1q[nt].w};
#pragma unroll
            for (int ks = 0; ks < 2; ++ks)
#pragma unroll
                for (int mt = 0; mt < 4; ++mt) {
                    const int r2 = p0 + mt * 16 + lane15;
                    const bf16x8 fb = *(const bf16x8*)
                        &feat_s[r2 * FSTRIDE + (((ks * 4 + quad) ^ swr) * 8)];
#pragma unroll
                    for (int nt = 0; nt < 2; ++nt)
                        acc[nt][mt] = __builtin_amdgcn_mfma_f32_16x16x32_bf16(
                            w1f[nt][ks], fb, acc[nt][mt], 0, 0, 0);
                }

            // silu-COMPUTE into regs (no LDS access): overlaps GEMM2(c-1)
            // of waves 0-3 that haven't reached barrier#1 yet.
            uint2 pk[2][4];
#pragma unroll
            for (int nt = 0; nt < 2; ++nt)
#pragma unroll
                for (int mt = 0; mt < 4; ++mt) {
                    float s[4];
#pragma unroll
                    for (int r = 0; r < 4; ++r) {
                        const float a = acc[nt][mt][r];     // = -log2e * preact
                        const float e = __builtin_amdgcn_exp2f(a);
                        s[r] = a * __builtin_amdgcn_rcpf(1.f + e);  // -1.4427*silu
                    }
                    pk[nt][mt].x = cvtpk(s[0], s[1]);
                    pk[nt][mt].y = cvtpk(s[2], s[3]);
                }

            __syncthreads();  // barrier#1: h_s(prev) fully consumed

            // only the 8 ds_write_b64 live between the barriers now
#pragma unroll
            for (int nt = 0; nt < 2; ++nt)
#pragma unroll
                for (int mt = 0; mt < 4; ++mt) {
                    const int pair = mt * 16 + lane15;
                    const int hbase = n0 + nt * 16 + quad * 4;
                    *(uint2*)&h_s[pair * HSTRIDE + hbase] = pk[nt][mt];
                }
            __syncthreads();  // barrier#2: h_s(c) ready

            // GEMM2: waves 0-3, one 16-pair M-tile each; K=256; W2 in regs
            if (wave < 4) {
                const int pw = wave * 16;
                f32x4 acc2 = (f32x4){b2v, b2v, b2v, b2v};
#pragma unroll
                for (int ks = 0; ks < 8; ++ks) {
                    const bf16x8 ha = *(const bf16x8*)&h_s[(pw + lane15) * HSTRIDE
                                                            + ks * 32 + quad * 8];
                    acc2 = __builtin_amdgcn_mfma_f32_16x16x32_bf16(ha, w2f[ks], acc2, 0, 0, 0);
                }
                if (lane15 < NH) {
                    float* op = out + (((size_t)b * NH + lane15) * NQ + i) * NK
                                + (p0 + pw + quad * 4);
                    *(float4*)op = make_float4(acc2[0], acc2[1], acc2[2], acc2[3]);
                }
            }
            // no end barrier: next chunk's GEMM1' touches only feat_s
        }
    }
}

extern "C" void kernel_launch(void* const* d_in, const int* in_sizes, int n_in,
                              void* d_out, int out_size, void* d_ws, size_t ws_size,
                              hipStream_t stream) {
    const float* q  = (const float*)d_in[0];
    const float* k  = (const float*)d_in[1];
    const float* W1 = (const float*)d_in[2];
    const float* b1 = (const float*)d_in[3];
    const float* W2 = (const float*)d_in[4];
    const float* b2 = (const float*)d_in[5];
    float* out = (float*)d_out;

    dim3 grid(NB * NQ / ROWS_PER_BLK);  // 512 blocks = 2/CU, one dispatch round
    dim3 block(512);                    // 8 waves: 16 waves/CU resident
    relfeat_mfma_kernel<<<grid, block, 0, stream>>>(q, k, W1, b1, W2, b2, out);
}